// Round 19
// baseline (1041.311 us; speedup 1.0000x reference)
//
#include <hip/hip_runtime.h>
#include <hip/hip_bf16.h>
#include <math.h>

#define BQ 2
#define SEQL 4096
#define DM 512
#define DIN 1024
#define DSTATE 128
#define NH 16
#define HD 64
#define DCONV 4
#define CONVDIM 1280
#define DINPROJ 2320
#define CHUNKL 128
#define NCHUNK 32
#define ROWS (BQ*SEQL)   // 8192
#define NPAD 2304        // 18*128: z (1024) + xBC (1280); dt cols via ln_dt_kernel

typedef __attribute__((ext_vector_type(8))) short short8;
typedef __attribute__((ext_vector_type(4))) short short4v;
typedef __attribute__((ext_vector_type(4))) float f32x4;

__device__ __forceinline__ short bfs(float f) {
  __hip_bfloat16 h = __float2bfloat16(f);
  short s; __builtin_memcpy(&s, &h, 2); return s;
}
__device__ __forceinline__ float sbf(short s) {
  __hip_bfloat16 h; __builtin_memcpy(&h, &s, 2); return __bfloat162float(h);
}

// ---------------- final LayerNorm (fp32 out) ----------------
__global__ __launch_bounds__(256) void ln_kernel(const float* __restrict__ in, const float* __restrict__ w,
                                                 const float* __restrict__ b, float* __restrict__ out,
                                                 __hip_bfloat16* __restrict__ outb) {
  int r = blockIdx.x;
  const float* x = in + (size_t)r * DM;
  float v[2];
  float s = 0.f, ss = 0.f;
  for (int i = 0; i < 2; i++) { v[i] = x[threadIdx.x + i*256]; s += v[i]; ss += v[i]*v[i]; }
  for (int o = 32; o > 0; o >>= 1) { s += __shfl_down(s, o); ss += __shfl_down(ss, o); }
  __shared__ float red[2][4];
  int lane = threadIdx.x & 63, wv = threadIdx.x >> 6;
  if (lane == 0) { red[0][wv] = s; red[1][wv] = ss; }
  __syncthreads();
  s  = red[0][0] + red[0][1] + red[0][2] + red[0][3];
  ss = red[1][0] + red[1][1] + red[1][2] + red[1][3];
  float mu = s * (1.f/DM);
  float var = ss * (1.f/DM) - mu*mu;
  float rstd = rsqrtf(var + 1e-5f);
  for (int i = 0; i < 2; i++) {
    int idx = threadIdx.x + i*256;
    float val = (v[i]-mu)*rstd*w[idx] + b[idx];
    out[(size_t)r*DM + idx] = val;
    if (outb) outb[(size_t)r*DM + idx] = __float2bfloat16(val);
  }
}

// ---------------- layer LayerNorm + exact dt, fused ----------------
__global__ __launch_bounds__(256) void ln_dt_kernel(const float* __restrict__ in, const float* __restrict__ w,
                                                    const float* __restrict__ b, const float* __restrict__ Wi,
                                                    const float* __restrict__ dtb,
                                                    __hip_bfloat16* __restrict__ outb, float* __restrict__ dtout) {
  int r = blockIdx.x;
  const float* x = in + (size_t)r * DM;
  __shared__ float sh[512];
  __shared__ float red2[2][4];
  __shared__ float red[16][17];
  int t = threadIdx.x;
  float v[2];
  float s = 0.f, ss = 0.f;
  for (int i = 0; i < 2; i++) { v[i] = x[t + i*256]; s += v[i]; ss += v[i]*v[i]; }
  for (int o = 32; o > 0; o >>= 1) { s += __shfl_down(s, o); ss += __shfl_down(ss, o); }
  int lane = t & 63, wv = t >> 6;
  if (lane == 0) { red2[0][wv] = s; red2[1][wv] = ss; }
  __syncthreads();
  s  = red2[0][0] + red2[0][1] + red2[0][2] + red2[0][3];
  ss = red2[1][0] + red2[1][1] + red2[1][2] + red2[1][3];
  float mu = s * (1.f/DM);
  float var = ss * (1.f/DM) - mu*mu;
  float rstd = rsqrtf(var + 1e-5f);
  for (int i = 0; i < 2; i++) {
    int idx = t + i*256;
    float val = (v[i]-mu)*rstd*w[idx] + b[idx];
    sh[idx] = val;
    outb[(size_t)r*DM + idx] = __float2bfloat16(val);
  }
  __syncthreads();
  int j = t >> 4, seg = t & 15;
  const float* wrow = Wi + (size_t)(2304 + j)*DM + seg*32;
  float p = 0.f;
  #pragma unroll
  for (int k = 0; k < 32; k++) p += sh[seg*32 + k] * wrow[k];
  red[j][seg] = p;
  __syncthreads();
  if (t < 16) {
    float vv = 0.f;
    for (int sgi = 0; sgi < 16; sgi++) vv += red[t][sgi];
    vv += dtb[t];
    dtout[r*NH + t] = (vv > 20.f) ? vv : log1pf(__expf(vv));
  }
}

// ---------------- weight fp32 -> bf16 conversions (once per call) ----------------
__global__ __launch_bounds__(256) void cvt_wi(const float* __restrict__ Wi, __hip_bfloat16* __restrict__ out) {
  int idx = blockIdx.x*256 + threadIdx.x;   // 6*NPAD*512
  int l = idx / (NPAD*DM);
  int r = idx - l*(NPAD*DM);
  int n = r >> 9, k = r & 511;
  out[idx] = __float2bfloat16(Wi[(size_t)l*DINPROJ*DM + (size_t)n*DM + k]);
}
// Wo with rms_w folded into the K (channel) axis: wo'[l,m,k] = Wo[l,m,k]*rw[l,k]
__global__ __launch_bounds__(256) void cvt_wo(const float* __restrict__ Wo, const float* __restrict__ rw,
                                              __hip_bfloat16* __restrict__ out) {
  size_t idx = (size_t)blockIdx.x*256 + threadIdx.x;  // 6*512*1024
  int l = (int)(idx / (DM*DIN));
  int k = (int)(idx & (DIN-1));
  out[idx] = __float2bfloat16(Wo[idx] * rw[l*DIN + k]);
}

// ---------------- in-proj GEMM: 64x128 tiles, 2304 blocks (9/CU work), XCD-pinned ----------------
__global__ __launch_bounds__(256) void gemm_nt_obf16(const __hip_bfloat16* __restrict__ A,
                                                     const __hip_bfloat16* __restrict__ Bw,
                                                     __hip_bfloat16* __restrict__ C) {
  __shared__ __hip_bfloat16 sA[64*64];
  __shared__ __hip_bfloat16 sB[128*64];
  const int N = NPAD, K = DM;
  int tid = threadIdx.x;
  int w = tid >> 6, lane = tid & 63;
  int quad = lane >> 4, l16 = lane & 15;
  int raw = blockIdx.x;              // 0..2303
  int xcd = raw & 7, seq = raw >> 3; // seq 0..287
  int panel = xcd*16 + seq/18;       // 0..127
  int row0 = panel * 64;
  int col0 = (seq % 18) * 128;
  int srow = lane >> 3;
  int schunk = lane & 7;
  f32x4 acc[2][4];
  #pragma unroll
  for (int i = 0; i < 2; i++)
    #pragma unroll
    for (int j = 0; j < 4; j++) acc[i][j] = (f32x4){0.f,0.f,0.f,0.f};
  int wrow = (w >> 1) * 32, wcol = (w & 1) * 64;
  for (int k0 = 0; k0 < K; k0 += 64) {
    #pragma unroll
    for (int j = 0; j < 2; j++) {          // A: 64 rows
      int r = w*16 + j*8 + srow;
      int gc = (schunk ^ (r & 7)) * 8;
      const __hip_bfloat16* ga = A + (size_t)(row0 + r)*K + k0 + gc;
      __builtin_amdgcn_global_load_lds((const __attribute__((address_space(1))) void*)ga,
          (__attribute__((address_space(3))) void*)(sA + (w*16 + j*8)*64), 16, 0, 0);
    }
    #pragma unroll
    for (int j = 0; j < 4; j++) {          // B: 128 rows
      int r = w*32 + j*8 + srow;
      int gc = (schunk ^ (r & 7)) * 8;
      const __hip_bfloat16* gb = Bw + (size_t)(col0 + r)*K + k0 + gc;
      __builtin_amdgcn_global_load_lds((const __attribute__((address_space(1))) void*)gb,
          (__attribute__((address_space(3))) void*)(sB + (w*32 + j*8)*64), 16, 0, 0);
    }
    __syncthreads();
    #pragma unroll
    for (int ks = 0; ks < 64; ks += 32) {
      short8 af[2], bfv[4];
      #pragma unroll
      for (int mt = 0; mt < 2; mt++) {
        int r = wrow + mt*16 + l16;
        int cch = (ks/8 + quad) ^ (r & 7);
        af[mt] = *(const short8*)(sA + r*64 + cch*8);
      }
      #pragma unroll
      for (int nt = 0; nt < 4; nt++) {
        int r = wcol + nt*16 + l16;
        int cch = (ks/8 + quad) ^ (r & 7);
        bfv[nt] = *(const short8*)(sB + r*64 + cch*8);
      }
      #pragma unroll
      for (int mt = 0; mt < 2; mt++)
        #pragma unroll
        for (int nt = 0; nt < 4; nt++)
          acc[mt][nt] = __builtin_amdgcn_mfma_f32_16x16x32_bf16(af[mt], bfv[nt], acc[mt][nt], 0, 0, 0);
    }
    __syncthreads();
  }
  #pragma unroll
  for (int mt = 0; mt < 2; mt++) {
    int r = row0 + wrow + mt*16 + quad*4;
    #pragma unroll
    for (int nt = 0; nt < 4; nt++) {
      int cidx = col0 + wcol + nt*16 + l16;
      __hip_bfloat16* cp = C + (size_t)r*N + cidx;
      #pragma unroll
      for (int rg = 0; rg < 4; rg++)
        cp[(size_t)rg*N] = __float2bfloat16(acc[mt][nt][rg]);
    }
  }
}

// ---------------- out-proj GEMM: 64x128 tiles, XCD-pinned; Cout = Cin + rs*(A·B) ----------------
// Layer 0 passes Cin = x (residual source), eliminating the prologue memcpy.
__global__ __launch_bounds__(256) void gemm_nt_addf32(const __hip_bfloat16* __restrict__ A,
                                                      const __hip_bfloat16* __restrict__ Bw,
                                                      const float* __restrict__ ssq,
                                                      const float* Cin,
                                                      float* Cout) {
  __shared__ __hip_bfloat16 sA[64*64];
  __shared__ __hip_bfloat16 sB[128*64];
  const int N = DM, K = DIN;
  int tid = threadIdx.x;
  int w = tid >> 6, lane = tid & 63;
  int quad = lane >> 4, l16 = lane & 15;
  int raw = blockIdx.x;            // 0..511
  int xcd = raw & 7, seq = raw >> 3;
  int panel = xcd*16 + (seq >> 2); // 0..127
  int row0 = panel * 64;
  int col0 = (seq & 3) * 128;
  int srow = lane >> 3;
  int schunk = lane & 7;
  f32x4 acc[2][4];
  #pragma unroll
  for (int i = 0; i < 2; i++)
    #pragma unroll
    for (int j = 0; j < 4; j++) acc[i][j] = (f32x4){0.f,0.f,0.f,0.f};
  int wrow = (w >> 1) * 32, wcol = (w & 1) * 64;
  for (int k0 = 0; k0 < K; k0 += 64) {
    #pragma unroll
    for (int j = 0; j < 2; j++) {          // A: 64 rows
      int r = w*16 + j*8 + srow;
      int gc = (schunk ^ (r & 7)) * 8;
      const __hip_bfloat16* ga = A + (size_t)(row0 + r)*K + k0 + gc;
      __builtin_amdgcn_global_load_lds((const __attribute__((address_space(1))) void*)ga,
          (__attribute__((address_space(3))) void*)(sA + (w*16 + j*8)*64), 16, 0, 0);
    }
    #pragma unroll
    for (int j = 0; j < 4; j++) {          // B: 128 rows
      int r = w*32 + j*8 + srow;
      int gc = (schunk ^ (r & 7)) * 8;
      const __hip_bfloat16* gb = Bw + (size_t)(col0 + r)*K + k0 + gc;
      __builtin_amdgcn_global_load_lds((const __attribute__((address_space(1))) void*)gb,
          (__attribute__((address_space(3))) void*)(sB + (w*32 + j*8)*64), 16, 0, 0);
    }
    __syncthreads();
    #pragma unroll
    for (int ks = 0; ks < 64; ks += 32) {
      short8 af[2], bfv[4];
      #pragma unroll
      for (int mt = 0; mt < 2; mt++) {
        int r = wrow + mt*16 + l16;
        int cch = (ks/8 + quad) ^ (r & 7);
        af[mt] = *(const short8*)(sA + r*64 + cch*8);
      }
      #pragma unroll
      for (int nt = 0; nt < 4; nt++) {
        int r = wcol + nt*16 + l16;
        int cch = (ks/8 + quad) ^ (r & 7);
        bfv[nt] = *(const short8*)(sB + r*64 + cch*8);
      }
      #pragma unroll
      for (int mt = 0; mt < 2; mt++)
        #pragma unroll
        for (int nt = 0; nt < 4; nt++)
          acc[mt][nt] = __builtin_amdgcn_mfma_f32_16x16x32_bf16(af[mt], bfv[nt], acc[mt][nt], 0, 0, 0);
    }
    __syncthreads();
  }
  #pragma unroll
  for (int mt = 0; mt < 2; mt++) {
    int r = row0 + wrow + mt*16 + quad*4;
    float rsv[4];
    #pragma unroll
    for (int rg = 0; rg < 4; rg++)
      rsv[rg] = rsqrtf(ssq[r + rg]*(1.f/DIN) + 1e-5f);
    #pragma unroll
    for (int nt = 0; nt < 4; nt++) {
      int cidx = col0 + wcol + nt*16 + l16;
      const float* ci = Cin + (size_t)r*N + cidx;
      float* co = Cout + (size_t)r*N + cidx;
      #pragma unroll
      for (int rg = 0; rg < 4; rg++)
        co[(size_t)rg*N] = ci[(size_t)rg*N] + rsv[rg]*acc[mt][nt][rg];
    }
  }
}

// ---------------- depthwise causal conv, LDS-tiled, bf16 input ----------------
__global__ __launch_bounds__(256) void conv_tiled(const __hip_bfloat16* __restrict__ zx, const float* __restrict__ cw,
                                                  const float* __restrict__ cb, const float* __restrict__ dt,
                                                  __hip_bfloat16* __restrict__ bcb,
                                                  __hip_bfloat16* __restrict__ xtg, __hip_bfloat16* __restrict__ btg) {
  __shared__ float tile[35][260];
  int c0 = blockIdx.x * 256;
  int r0 = blockIdx.y * 32;
  int b = r0 >> 12, l0 = r0 & 4095;
  int t = threadIdx.x;
  for (int i = t; i < 35*64; i += 256) {
    int lr = i >> 6, c4 = (i & 63) * 4;
    int l = l0 - 3 + lr;
    float4 v = make_float4(0.f, 0.f, 0.f, 0.f);
    if (l >= 0) {
      short4v s = *(const short4v*)((const short*)zx + ((size_t)(b<<12) + l)*NPAD + 1024 + c0 + c4);
      v = make_float4(sbf(s[0]), sbf(s[1]), sbf(s[2]), sbf(s[3]));
    }
    *(float4*)&tile[lr][c4] = v;
  }
  __syncthreads();
  int c = c0 + t;
  float w0 = cw[c*4+0], w1 = cw[c*4+1], w2 = cw[c*4+2], w3 = cw[c*4+3];
  float bias = cb[c];
  float x0 = tile[0][t], x1 = tile[1][t], x2 = tile[2][t];
  if (c0 < DIN) {
    int h = c >> 6;
    const float* dtp = dt + (size_t)r0*NH + h;
    __hip_bfloat16* xo = xtg + ((size_t)(b*DIN + c))*SEQL + l0;
    for (int lb = 0; lb < 4; lb++) {
      short8 pk;
      #pragma unroll
      for (int jj = 0; jj < 8; jj++) {
        int l = lb*8 + jj;
        float x3 = tile[l+3][t];
        float acc = bias + w0*x0 + w1*x1 + w2*x2 + w3*x3;
        float sv = acc / (1.f + __expf(-acc));
        pk[jj] = bfs(sv * dtp[(size_t)l*NH]);
        x0 = x1; x1 = x2; x2 = x3;
      }
      *(short8*)(xo + lb*8) = pk;
    }
  } else {
    int n = c - DIN;
    __hip_bfloat16* bo = (n < DSTATE) ? (btg + ((size_t)(b*DSTATE + n))*SEQL + l0) : nullptr;
    for (int lb = 0; lb < 4; lb++) {
      short8 pk;
      #pragma unroll
      for (int jj = 0; jj < 8; jj++) {
        int l = lb*8 + jj;
        float x3 = tile[l+3][t];
        float acc = bias + w0*x0 + w1*x1 + w2*x2 + w3*x3;
        float sv = acc / (1.f + __expf(-acc));
        short bv = bfs(sv);
        bcb[(size_t)(r0 + l)*256 + n] = *(__hip_bfloat16*)&bv;
        pk[jj] = bv;
        x0 = x1; x1 = x2; x2 = x3;
      }
      if (bo) *(short8*)(bo + lb*8) = pk;
    }
  }
}

// ---------------- SSD pre-scan: chunk states (step4), bf16 out, 512 thr / 8 waves ----------------
__global__ __launch_bounds__(512, 6) void ssd_states_mfma(const __hip_bfloat16* __restrict__ xtg,
                                                          const __hip_bfloat16* __restrict__ btg,
                                                          const float* __restrict__ dt,
                                                          const float* __restrict__ Alog,
                                                          __hip_bfloat16* __restrict__ stb,
                                                          float* __restrict__ acs_buf,
                                                          float* __restrict__ alast) {
  __shared__ short sBt[128][136];   // B^T [n][q] (pure copy)
  __shared__ short sXw[64][136];    // (X·w)^T [p][q]
  __shared__ float sa[128], sw[128];
  int raw = blockIdx.x;
  int bc = (raw & 7) + ((raw >> 7) << 3);
  int h = (raw >> 3) & 15;
  int b = bc >> 5, c = bc & 31;
  int sblk = bc*16 + h;
  int t = threadIdx.x;
  int w = t >> 6, lane = t & 63, quad = lane >> 4, l16 = lane & 15;
  size_t row0 = (size_t)(b*SEQL + c*CHUNKL);
  float Ah = -__expf(Alog[h]);
  if (t < 64) {
    float d0 = dt[(row0 + 2*t)*NH + h], d1 = dt[(row0 + 2*t + 1)*NH + h];
    float v0 = d0 * Ah, v1 = d1 * Ah;
    float s2 = v0 + v1;
    #pragma unroll
    for (int off = 1; off < 64; off <<= 1) {
      float tmp = __shfl_up(s2, off);
      if (t >= off) s2 += tmp;
    }
    float tot = __shfl(s2, 63);
    float pre = s2 - (v0 + v1);
    float a0 = pre + v0, a1 = pre + v0 + v1;
    sa[2*t] = a0; sa[2*t+1] = a1;
    sw[2*t] = __expf(tot - a0); sw[2*t+1] = __expf(tot - a1);
    acs_buf[(size_t)sblk*128 + 2*t]   = a0;
    acs_buf[(size_t)sblk*128 + 2*t+1] = a1;
    if (t == 63) alast[(b*NH + h)*NCHUNK + c] = tot;
  }
  __syncthreads();
  {
    const __hip_bfloat16* xb = xtg + ((size_t)(b*DIN + h*HD))*SEQL + c*CHUNKL;
    for (int i = t; i < 64*16; i += 512) {
      int p = i >> 4, q8 = (i & 15) * 8;
      short8 v = *(const short8*)(xb + (size_t)p*SEQL + q8);
      short8 o;
      #pragma unroll
      for (int j = 0; j < 8; j++) o[j] = bfs(sbf(v[j]) * sw[q8 + j]);
      *(short8*)&sXw[p][q8] = o;
    }
    const __hip_bfloat16* bb = btg + ((size_t)(b*DSTATE))*SEQL + c*CHUNKL;
    for (int i = t; i < 128*16; i += 512) {
      int n = i >> 4, q8 = (i & 15) * 8;
      *(short8*)&sBt[n][q8] = *(const short8*)(bb + (size_t)n*SEQL + q8);
    }
  }
  __syncthreads();
  int pt4 = w >> 1, nt4 = (w & 1) * 4;
  f32x4 st[4];
  #pragma unroll
  for (int j = 0; j < 4; j++) st[j] = (f32x4){0.f,0.f,0.f,0.f};
  #pragma unroll
  for (int ks = 0; ks < 128; ks += 32) {
    short8 af = *(const short8*)&sXw[pt4*16 + l16][ks + quad*8];
    #pragma unroll
    for (int j = 0; j < 4; j++) {
      short8 bfv = *(const short8*)&sBt[(nt4+j)*16 + l16][ks + quad*8];
      st[j] = __builtin_amdgcn_mfma_f32_16x16x32_bf16(af, bfv, st[j], 0, 0, 0);
    }
  }
  __hip_bfloat16* sp = stb + (size_t)sblk*(HD*DSTATE);
  #pragma unroll
  for (int j = 0; j < 4; j++) {
    int n = (nt4+j)*16 + l16;
    #pragma unroll
    for (int rg = 0; rg < 4; rg++) {
      int p = pt4*16 + quad*4 + rg;
      sp[(size_t)p*DSTATE + n] = __float2bfloat16(st[j][rg]);
    }
  }
}

// ---------------- inter-chunk scan: bf16 in-place (chunk-state -> init-state); zeroes ssq ----------------
__global__ __launch_bounds__(256) void ssd_scan2(__hip_bfloat16* __restrict__ stb, const float* __restrict__ alast,
                                                 float* __restrict__ ssq) {
  int idx = blockIdx.x*256 + threadIdx.x;     // 2*16*8192
  if (idx < ROWS) ssq[idx] = 0.f;
  int b = idx >> 17;
  int h = (idx >> 13) & 15;
  int pn = idx & 8191;
  const float* al = alast + (b*NH + h)*NCHUNK;
  float S = 0.f;
  for (int c = 0; c < NCHUNK; c++) {
    size_t base = ((size_t)((b*NCHUNK + c)*NH + h))*8192 + pn;
    float dec = __expf(al[c]);
    float tmp = __bfloat162float(stb[base]);
    stb[base] = __float2bfloat16(S);
    S = dec*S + tmp;
  }
}

// ---------------- SSD post-scan + gate, double-buffered per-head X/S staging ----------------
__global__ __launch_bounds__(1024, 4) void ssd_post_mfma(const __hip_bfloat16* __restrict__ bcb,
                                                         const __hip_bfloat16* __restrict__ xtg,
                                                         const float* __restrict__ dt,
                                                         const __hip_bfloat16* __restrict__ stb,
                                                         const float* __restrict__ acs_buf,
                                                         const float* __restrict__ Dvec,
                                                         const __hip_bfloat16* __restrict__ zx,
                                                         float* __restrict__ ssq,
                                                         __hip_bfloat16* __restrict__ Y) {
  __shared__ short sM[128][136];      // B panel during G; M_h per head after
  __shared__ short sXt[2][64][136];   // X^T (dt-scaled), double-buffered
  __shared__ short sS[2][64][136];    // scanned init-state, double-buffered
  __shared__ float sa[4][128];
  __shared__ float sdt4[4][128];
  __shared__ float ssrow[128];
  int raw = blockIdx.x;            // 0..255
  int xcd = raw & 7, slot = raw >> 3;
  int bc = xcd*8 + (slot >> 2);    // bijective: 4 blocks of one (b,c) on one XCD
  int hg = slot & 3;
  int b = bc >> 5, c = bc & 31;
  int t = threadIdx.x;
  int w = t >> 6, lane = t & 63, quad = lane >> 4, l16 = lane & 15;
  size_t row0 = (size_t)(b*SEQL + c*CHUNKL);
  const __hip_bfloat16* bcrow = bcb + row0*256;
  int mt = w >> 1, nt1 = (w & 1) * 4, pt3 = (w & 1) * 2;
  if (t < 128) ssrow[t] = 0.f;
  // hoist C fragments into registers
  short8 af[4];
  #pragma unroll
  for (int k = 0; k < 4; k++)
    af[k] = *(const short8*)(bcrow + (size_t)(mt*16 + l16)*256 + 128 + k*32 + quad*8);
  // stage B panel into sM region
  for (int i = t; i < 128*16; i += 1024) {
    int q = i >> 4, n8 = (i & 15) * 8;
    *(short8*)&sM[q][n8] = *(const short8*)(bcrow + (size_t)q*256 + n8);
  }
  // stage sa/sdt for the 4 heads
  if (t < 512) {
    int hh = t >> 7, q = t & 127;
    int h = hg*4 + hh;
    sa[hh][q]   = acs_buf[(size_t)(bc*16 + h)*128 + q];
    sdt4[hh][q] = dt[(row0 + q)*NH + h];
  }
  // stage head 0's X and S into buffer 0
  {
    int h = hg*4;
    const __hip_bfloat16* xb = xtg + ((size_t)(b*DIN + h*HD))*SEQL + c*CHUNKL;
    int p = t >> 4, q8 = (t & 15) * 8;
    *(short8*)&sXt[0][p][q8] = *(const short8*)(xb + (size_t)p*SEQL + q8);
    const __hip_bfloat16* sbase = stb + (size_t)(bc*16 + h)*(HD*DSTATE);
    *(short8*)&sS[0][p][q8] = *(const short8*)(sbase + (size_t)p*DSTATE + q8);
  }
  __syncthreads();
  // G = C·B^T once — kept live in g[4] for all 4 heads
  f32x4 g[4];
  #pragma unroll
  for (int j = 0; j < 4; j++) g[j] = (f32x4){0.f,0.f,0.f,0.f};
  #pragma unroll
  for (int ks = 0; ks < 4; ks++) {
    #pragma unroll
    for (int j = 0; j < 4; j++) {
      short8 bfv = *(const short8*)&sM[(nt1+j)*16 + l16][ks*32 + quad*8];
      g[j] = __builtin_amdgcn_mfma_f32_16x16x32_bf16(af[ks], bfv, g[j], 0, 0, 0);
    }
  }
  __syncthreads();   // B reads done; sM region free for M
  for (int hh = 0; hh < 4; hh++) {
    int h = hg*4 + hh;
    int cur = hh & 1;
    // write M_h = L_h ⊙ G into sM
    #pragma unroll
    for (int j = 0; j < 4; j++) {
      int s = (nt1+j)*16 + l16;
      #pragma unroll
      for (int rg = 0; rg < 4; rg++) {
        int q = mt*16 + quad*4 + rg;
        float m = (s <= q) ? g[j][rg] * __expf(sa[hh][q] - sa[hh][s]) : 0.f;
        sM[q][s] = bfs(m);
      }
    }
    __syncthreads();   // (A) publishes M_h + previously staged X/S[cur]
    // issue next head's X/S staging into the OTHER buffer (overlaps with MFMA below)
    if (hh < 3) {
      int h2 = h + 1;
      const __hip_bfloat16* xb = xtg + ((size_t)(b*DIN + h2*HD))*SEQL + c*CHUNKL;
      int p = t >> 4, q8 = (t & 15) * 8;
      *(short8*)&sXt[cur^1][p][q8] = *(const short8*)(xb + (size_t)p*SEQL + q8);
      const __hip_bfloat16* sbase2 = stb + (size_t)(bc*16 + h2)*(HD*DSTATE);
      *(short8*)&sS[cur^1][p][q8] = *(const short8*)(sbase2 + (size_t)p*DSTATE + q8);
    }
    // Ydiag = M_h·X_h  and  Yoff = C·S_h  (read buffer cur)
    f32x4 y4[2], yo[2];
    y4[0] = (f32x4){0.f,0.f,0.f,0.f}; y4[1] = (f32x4){0.f,0.f,0.f,0.f};
    yo[0] = (f32x4){0.f,0.f,0.f,0.f}; yo[1] = (f32x4){0.f,0.f,0.f,0.f};
    #pragma unroll
    for (int ks = 0; ks < 4; ks++) {
      short8 mf = *(const short8*)&sM[mt*16 + l16][ks*32 + quad*8];
      #pragma unroll
      for (int j = 0; j < 2; j++) {
        short8 xv = *(const short8*)&sXt[cur][(pt3+j)*16 + l16][ks*32 + quad*8];
        y4[j] = __builtin_amdgcn_mfma_f32_16x16x32_bf16(mf, xv, y4[j], 0, 0, 0);
        short8 sv = *(const short8*)&sS[cur][(pt3+j)*16 + l16][ks*32 + quad*8];
        yo[j] = __builtin_amdgcn_mfma_f32_16x16x32_bf16(af[ks], sv, yo[j], 0, 0, 0);
      }
    }
    // epilogue: v = (Yd + e^a·Yoff + D·x) * silu(z); write bf16 yz; reduce Σv² per row
    float Dh = Dvec[h];
    float part[4];
    #pragma unroll
    for (int rg = 0; rg < 4; rg++) {
      int q = mt*16 + quad*4 + rg;
      float ea = __expf(sa[hh][q]);
      float drdt = Dh / sdt4[hh][q];
      float pr = 0.f;
      #pragma unroll
      for (int j = 0; j < 2; j++) {
        int p = (pt3+j)*16 + l16;
        int ch = h*HD + p;
        float yv = y4[j][rg] + ea*yo[j][rg] + drdt*sbf(sXt[cur][p][q]);
        float z = sbf(*((const short*)zx + (row0+q)*NPAD + ch));
        float v = yv * z / (1.f + __expf(-z));
        Y[(row0 + q)*DIN + ch] = __float2bfloat16(v);
        pr += v*v;
      }
      part[rg] = pr;
    }
    #pragma unroll
    for (int rg = 0; rg < 4; rg++) {
      float pv = part[rg];
      #pragma unroll
      for (int off = 1; off < 16; off <<= 1) pv += __shfl_xor(pv, off);
      if (l16 == 0) atomicAdd(&ssrow[mt*16 + quad*4 + rg], pv);
    }
    __syncthreads();   // (B) sM reads done before next M write; staged X/S drained
  }
  if (t < 128) atomicAdd(&ssq[row0 + t], ssrow[t]);
}

extern "C" void kernel_launch(void* const* d_in, const int* in_sizes, int n_in,
                              void* d_out, int out_size, void* d_ws, size_t ws_size,
                              hipStream_t stream) {
  (void)in_sizes; (void)n_in; (void)out_size; (void)ws_size;
  const float* x    = (const float*)d_in[0];
  const float* Wi   = (const float*)d_in[1];
  const float* cw   = (const float*)d_in[2];
  const float* cb   = (const float*)d_in[3];
  const float* dtb  = (const float*)d_in[4];
  const float* Alog = (const float*)d_in[5];
  const float* Dv   = (const float*)d_in[6];
  const float* rw   = (const float*)d_in[7];
  const float* Wo   = (const float*)d_in[8];
  const float* lnw  = (const float*)d_in[9];
  const float* lnb  = (const float*)d_in[10];
  const float* flnw = (const float*)d_in[11];
  const float* flnb = (const float*)d_in[12];
  float* out = (float*)d_out;

  float* p = (float*)d_ws;
  float* buf_h   = p; p += (size_t)ROWS*DM;
  float* buf_dt  = p; p += (size_t)ROWS*NH;
  float* buf_acs = p; p += (size_t)BQ*NCHUNK*NH*CHUNKL;
  float* buf_al  = p; p += (size_t)BQ*NH*NCHUNK;
  float* buf_ssq = p; p += (size_t)ROWS;
  __hip_bfloat16* bp = (__hip_bfloat16*)p;
  __hip_bfloat16* buf_zx = bp; bp += (size_t)ROWS*NPAD;      // bf16 zx (z | xBC), stride 2304
  __hip_bfloat16* wi_b = bp; bp += (size_t)6*NPAD*DM;
  __hip_bfloat16* wo_b = bp; bp += (size_t)6*DM*DIN;
  __hip_bfloat16* hn_b = bp;                                 // shares region with yz
  __hip_bfloat16* Ybuf = bp; bp += (size_t)ROWS*DIN;
  __hip_bfloat16* bcb  = bp; bp += (size_t)ROWS*256;         // B|C natural bf16
  __hip_bfloat16* xtg  = bp; bp += (size_t)BQ*DIN*SEQL;      // X^T * dt, bf16
  __hip_bfloat16* btg  = bp; bp += (size_t)BQ*DSTATE*SEQL;   // B^T bf16
  __hip_bfloat16* stb  = bp; bp += (size_t)BQ*NCHUNK*NH*HD*DSTATE; // chunk states -> init states (in-place scan)

  cvt_wi<<<6*NPAD*DM/256, 256, 0, stream>>>(Wi, wi_b);
  cvt_wo<<<6*DM*DIN/256, 256, 0, stream>>>(Wo, rw, wo_b);

  for (int i = 0; i < 6; i++) {
    const float* hin = (i == 0) ? x : buf_h;
    ln_dt_kernel<<<ROWS, 256, 0, stream>>>(hin, lnw + i*DM, lnb + i*DM,
                                           Wi + (size_t)i*DINPROJ*DM, dtb + i*NH, hn_b, buf_dt);
    gemm_nt_obf16<<<2304, 256, 0, stream>>>(
        hn_b, wi_b + (size_t)i*NPAD*DM, buf_zx);
    conv_tiled<<<dim3(CONVDIM/256, ROWS/32), 256, 0, stream>>>(
        buf_zx, cw + (size_t)i*CONVDIM*DCONV, cb + i*CONVDIM, buf_dt,
        bcb, xtg, btg);
    ssd_states_mfma<<<BQ*NCHUNK*NH, 512, 0, stream>>>(
        xtg, btg, buf_dt, Alog + i*NH, stb, buf_acs, buf_al);
    ssd_scan2<<<BQ*NH*HD*DSTATE/256, 256, 0, stream>>>(stb, buf_al, buf_ssq);
    ssd_post_mfma<<<BQ*NCHUNK*4, 1024, 0, stream>>>(
        bcb, xtg, buf_dt, stb, buf_acs, Dv + i*NH, buf_zx, buf_ssq, Ybuf);
    gemm_nt_addf32<<<512, 256, 0, stream>>>(
        Ybuf, wo_b + (size_t)i*DM*DIN, buf_ssq, hin, buf_h);
  }
  ln_kernel<<<ROWS, 256, 0, stream>>>(buf_h, flnw, flnb, out, nullptr);
}

// Round 21
// 938.087 us; speedup vs baseline: 1.1100x; 1.1100x over previous
//
#include <hip/hip_runtime.h>
#include <hip/hip_bf16.h>
#include <math.h>

#define BQ 2
#define SEQL 4096
#define DM 512
#define DIN 1024
#define DSTATE 128
#define NH 16
#define HD 64
#define DCONV 4
#define CONVDIM 1280
#define DINPROJ 2320
#define CHUNKL 128
#define NCHUNK 32
#define ROWS (BQ*SEQL)   // 8192
#define NPAD 2304        // 18*128: z (1024) + xBC (1280); dt cols via ln_dt_kernel

typedef __attribute__((ext_vector_type(8))) short short8;
typedef __attribute__((ext_vector_type(4))) short short4v;
typedef __attribute__((ext_vector_type(4))) float f32x4;

__device__ __forceinline__ short bfs(float f) {
  __hip_bfloat16 h = __float2bfloat16(f);
  short s; __builtin_memcpy(&s, &h, 2); return s;
}
__device__ __forceinline__ float sbf(short s) {
  __hip_bfloat16 h; __builtin_memcpy(&h, &s, 2); return __bfloat162float(h);
}

// ---------------- final LayerNorm (fp32 out) ----------------
__global__ __launch_bounds__(256) void ln_kernel(const float* __restrict__ in, const float* __restrict__ w,
                                                 const float* __restrict__ b, float* __restrict__ out,
                                                 __hip_bfloat16* __restrict__ outb) {
  int r = blockIdx.x;
  const float* x = in + (size_t)r * DM;
  float v[2];
  float s = 0.f, ss = 0.f;
  for (int i = 0; i < 2; i++) { v[i] = x[threadIdx.x + i*256]; s += v[i]; ss += v[i]*v[i]; }
  for (int o = 32; o > 0; o >>= 1) { s += __shfl_down(s, o); ss += __shfl_down(ss, o); }
  __shared__ float red[2][4];
  int lane = threadIdx.x & 63, wv = threadIdx.x >> 6;
  if (lane == 0) { red[0][wv] = s; red[1][wv] = ss; }
  __syncthreads();
  s  = red[0][0] + red[0][1] + red[0][2] + red[0][3];
  ss = red[1][0] + red[1][1] + red[1][2] + red[1][3];
  float mu = s * (1.f/DM);
  float var = ss * (1.f/DM) - mu*mu;
  float rstd = rsqrtf(var + 1e-5f);
  for (int i = 0; i < 2; i++) {
    int idx = threadIdx.x + i*256;
    float val = (v[i]-mu)*rstd*w[idx] + b[idx];
    out[(size_t)r*DM + idx] = val;
    if (outb) outb[(size_t)r*DM + idx] = __float2bfloat16(val);
  }
}

// ---------------- layer LayerNorm + exact dt, fused ----------------
// v2: dt mat-vec iterates kk = seg + 16*k  -> LDS reads hit 16 distinct banks
// (broadcast across j-groups) and Wi reads are 64B-contiguous per j-group.
// Old seg*32+k form was a 16-way bank conflict x32 iters (7.4e6 conflict cycles).
__global__ __launch_bounds__(256) void ln_dt_kernel(const float* __restrict__ in, const float* __restrict__ w,
                                                    const float* __restrict__ b, const float* __restrict__ Wi,
                                                    const float* __restrict__ dtb,
                                                    __hip_bfloat16* __restrict__ outb, float* __restrict__ dtout) {
  int r = blockIdx.x;
  const float* x = in + (size_t)r * DM;
  __shared__ float sh[512];
  __shared__ float red2[2][4];
  __shared__ float red[16][17];
  int t = threadIdx.x;
  float v[2];
  float s = 0.f, ss = 0.f;
  for (int i = 0; i < 2; i++) { v[i] = x[t + i*256]; s += v[i]; ss += v[i]*v[i]; }
  for (int o = 32; o > 0; o >>= 1) { s += __shfl_down(s, o); ss += __shfl_down(ss, o); }
  int lane = t & 63, wv = t >> 6;
  if (lane == 0) { red2[0][wv] = s; red2[1][wv] = ss; }
  __syncthreads();
  s  = red2[0][0] + red2[0][1] + red2[0][2] + red2[0][3];
  ss = red2[1][0] + red2[1][1] + red2[1][2] + red2[1][3];
  float mu = s * (1.f/DM);
  float var = ss * (1.f/DM) - mu*mu;
  float rstd = rsqrtf(var + 1e-5f);
  for (int i = 0; i < 2; i++) {
    int idx = t + i*256;
    float val = (v[i]-mu)*rstd*w[idx] + b[idx];
    sh[idx] = val;
    outb[(size_t)r*DM + idx] = __float2bfloat16(val);
  }
  __syncthreads();
  int j = t >> 4, seg = t & 15;
  const float* wrow = Wi + (size_t)(2304 + j)*DM;
  float p = 0.f;
  #pragma unroll
  for (int k = 0; k < 32; k++) {
    int kk = seg + k*16;
    p += sh[kk] * wrow[kk];
  }
  red[j][seg] = p;
  __syncthreads();
  if (t < 16) {
    float vv = 0.f;
    for (int sgi = 0; sgi < 16; sgi++) vv += red[t][sgi];
    vv += dtb[t];
    dtout[r*NH + t] = (vv > 20.f) ? vv : log1pf(__expf(vv));
  }
}

// ---------------- weight fp32 -> bf16 conversions (once per call) ----------------
__global__ __launch_bounds__(256) void cvt_wi(const float* __restrict__ Wi, __hip_bfloat16* __restrict__ out) {
  int idx = blockIdx.x*256 + threadIdx.x;   // 6*NPAD*512
  int l = idx / (NPAD*DM);
  int r = idx - l*(NPAD*DM);
  int n = r >> 9, k = r & 511;
  out[idx] = __float2bfloat16(Wi[(size_t)l*DINPROJ*DM + (size_t)n*DM + k]);
}
// Wo with rms_w folded into the K (channel) axis: wo'[l,m,k] = Wo[l,m,k]*rw[l,k]
__global__ __launch_bounds__(256) void cvt_wo(const float* __restrict__ Wo, const float* __restrict__ rw,
                                              __hip_bfloat16* __restrict__ out) {
  size_t idx = (size_t)blockIdx.x*256 + threadIdx.x;  // 6*512*1024
  int l = (int)(idx / (DM*DIN));
  int k = (int)(idx & (DIN-1));
  out[idx] = __float2bfloat16(Wo[idx] * rw[l*DIN + k]);
}

// ---------------- in-proj GEMM: 64x128 tiles, 2304 blocks (9/CU work), XCD-pinned ----------------
__global__ __launch_bounds__(256) void gemm_nt_obf16(const __hip_bfloat16* __restrict__ A,
                                                     const __hip_bfloat16* __restrict__ Bw,
                                                     __hip_bfloat16* __restrict__ C) {
  __shared__ __hip_bfloat16 sA[64*64];
  __shared__ __hip_bfloat16 sB[128*64];
  const int N = NPAD, K = DM;
  int tid = threadIdx.x;
  int w = tid >> 6, lane = tid & 63;
  int quad = lane >> 4, l16 = lane & 15;
  int raw = blockIdx.x;              // 0..2303
  int xcd = raw & 7, seq = raw >> 3; // seq 0..287
  int panel = xcd*16 + seq/18;       // 0..127
  int row0 = panel * 64;
  int col0 = (seq % 18) * 128;
  int srow = lane >> 3;
  int schunk = lane & 7;
  f32x4 acc[2][4];
  #pragma unroll
  for (int i = 0; i < 2; i++)
    #pragma unroll
    for (int j = 0; j < 4; j++) acc[i][j] = (f32x4){0.f,0.f,0.f,0.f};
  int wrow = (w >> 1) * 32, wcol = (w & 1) * 64;
  for (int k0 = 0; k0 < K; k0 += 64) {
    #pragma unroll
    for (int j = 0; j < 2; j++) {          // A: 64 rows
      int r = w*16 + j*8 + srow;
      int gc = (schunk ^ (r & 7)) * 8;
      const __hip_bfloat16* ga = A + (size_t)(row0 + r)*K + k0 + gc;
      __builtin_amdgcn_global_load_lds((const __attribute__((address_space(1))) void*)ga,
          (__attribute__((address_space(3))) void*)(sA + (w*16 + j*8)*64), 16, 0, 0);
    }
    #pragma unroll
    for (int j = 0; j < 4; j++) {          // B: 128 rows
      int r = w*32 + j*8 + srow;
      int gc = (schunk ^ (r & 7)) * 8;
      const __hip_bfloat16* gb = Bw + (size_t)(col0 + r)*K + k0 + gc;
      __builtin_amdgcn_global_load_lds((const __attribute__((address_space(1))) void*)gb,
          (__attribute__((address_space(3))) void*)(sB + (w*32 + j*8)*64), 16, 0, 0);
    }
    __syncthreads();
    #pragma unroll
    for (int ks = 0; ks < 64; ks += 32) {
      short8 af[2], bfv[4];
      #pragma unroll
      for (int mt = 0; mt < 2; mt++) {
        int r = wrow + mt*16 + l16;
        int cch = (ks/8 + quad) ^ (r & 7);
        af[mt] = *(const short8*)(sA + r*64 + cch*8);
      }
      #pragma unroll
      for (int nt = 0; nt < 4; nt++) {
        int r = wcol + nt*16 + l16;
        int cch = (ks/8 + quad) ^ (r & 7);
        bfv[nt] = *(const short8*)(sB + r*64 + cch*8);
      }
      #pragma unroll
      for (int mt = 0; mt < 2; mt++)
        #pragma unroll
        for (int nt = 0; nt < 4; nt++)
          acc[mt][nt] = __builtin_amdgcn_mfma_f32_16x16x32_bf16(af[mt], bfv[nt], acc[mt][nt], 0, 0, 0);
    }
    __syncthreads();
  }
  #pragma unroll
  for (int mt = 0; mt < 2; mt++) {
    int r = row0 + wrow + mt*16 + quad*4;
    #pragma unroll
    for (int nt = 0; nt < 4; nt++) {
      int cidx = col0 + wcol + nt*16 + l16;
      __hip_bfloat16* cp = C + (size_t)r*N + cidx;
      #pragma unroll
      for (int rg = 0; rg < 4; rg++)
        cp[(size_t)rg*N] = __float2bfloat16(acc[mt][nt][rg]);
    }
  }
}

// ---------------- out-proj GEMM: 64x128 tiles, XCD-pinned; Cout = Cin + rs*(A·B) ----------------
// Layer 0 passes Cin = x (residual source), eliminating the prologue memcpy.
__global__ __launch_bounds__(256) void gemm_nt_addf32(const __hip_bfloat16* __restrict__ A,
                                                      const __hip_bfloat16* __restrict__ Bw,
                                                      const float* __restrict__ ssq,
                                                      const float* Cin,
                                                      float* Cout) {
  __shared__ __hip_bfloat16 sA[64*64];
  __shared__ __hip_bfloat16 sB[128*64];
  const int N = DM, K = DIN;
  int tid = threadIdx.x;
  int w = tid >> 6, lane = tid & 63;
  int quad = lane >> 4, l16 = lane & 15;
  int raw = blockIdx.x;            // 0..511
  int xcd = raw & 7, seq = raw >> 3;
  int panel = xcd*16 + (seq >> 2); // 0..127
  int row0 = panel * 64;
  int col0 = (seq & 3) * 128;
  int srow = lane >> 3;
  int schunk = lane & 7;
  f32x4 acc[2][4];
  #pragma unroll
  for (int i = 0; i < 2; i++)
    #pragma unroll
    for (int j = 0; j < 4; j++) acc[i][j] = (f32x4){0.f,0.f,0.f,0.f};
  int wrow = (w >> 1) * 32, wcol = (w & 1) * 64;
  for (int k0 = 0; k0 < K; k0 += 64) {
    #pragma unroll
    for (int j = 0; j < 2; j++) {          // A: 64 rows
      int r = w*16 + j*8 + srow;
      int gc = (schunk ^ (r & 7)) * 8;
      const __hip_bfloat16* ga = A + (size_t)(row0 + r)*K + k0 + gc;
      __builtin_amdgcn_global_load_lds((const __attribute__((address_space(1))) void*)ga,
          (__attribute__((address_space(3))) void*)(sA + (w*16 + j*8)*64), 16, 0, 0);
    }
    #pragma unroll
    for (int j = 0; j < 4; j++) {          // B: 128 rows
      int r = w*32 + j*8 + srow;
      int gc = (schunk ^ (r & 7)) * 8;
      const __hip_bfloat16* gb = Bw + (size_t)(col0 + r)*K + k0 + gc;
      __builtin_amdgcn_global_load_lds((const __attribute__((address_space(1))) void*)gb,
          (__attribute__((address_space(3))) void*)(sB + (w*32 + j*8)*64), 16, 0, 0);
    }
    __syncthreads();
    #pragma unroll
    for (int ks = 0; ks < 64; ks += 32) {
      short8 af[2], bfv[4];
      #pragma unroll
      for (int mt = 0; mt < 2; mt++) {
        int r = wrow + mt*16 + l16;
        int cch = (ks/8 + quad) ^ (r & 7);
        af[mt] = *(const short8*)(sA + r*64 + cch*8);
      }
      #pragma unroll
      for (int nt = 0; nt < 4; nt++) {
        int r = wcol + nt*16 + l16;
        int cch = (ks/8 + quad) ^ (r & 7);
        bfv[nt] = *(const short8*)(sB + r*64 + cch*8);
      }
      #pragma unroll
      for (int mt = 0; mt < 2; mt++)
        #pragma unroll
        for (int nt = 0; nt < 4; nt++)
          acc[mt][nt] = __builtin_amdgcn_mfma_f32_16x16x32_bf16(af[mt], bfv[nt], acc[mt][nt], 0, 0, 0);
    }
    __syncthreads();
  }
  #pragma unroll
  for (int mt = 0; mt < 2; mt++) {
    int r = row0 + wrow + mt*16 + quad*4;
    float rsv[4];
    #pragma unroll
    for (int rg = 0; rg < 4; rg++)
      rsv[rg] = rsqrtf(ssq[r + rg]*(1.f/DIN) + 1e-5f);
    #pragma unroll
    for (int nt = 0; nt < 4; nt++) {
      int cidx = col0 + wcol + nt*16 + l16;
      const float* ci = Cin + (size_t)r*N + cidx;
      float* co = Cout + (size_t)r*N + cidx;
      #pragma unroll
      for (int rg = 0; rg < 4; rg++)
        co[(size_t)rg*N] = ci[(size_t)rg*N] + rsv[rg]*acc[mt][nt][rg];
    }
  }
}

// ---------------- depthwise causal conv, LDS-tiled, bf16 input ----------------
__global__ __launch_bounds__(256) void conv_tiled(const __hip_bfloat16* __restrict__ zx, const float* __restrict__ cw,
                                                  const float* __restrict__ cb, const float* __restrict__ dt,
                                                  __hip_bfloat16* __restrict__ bcb,
                                                  __hip_bfloat16* __restrict__ xtg, __hip_bfloat16* __restrict__ btg) {
  __shared__ float tile[35][260];
  int c0 = blockIdx.x * 256;
  int r0 = blockIdx.y * 32;
  int b = r0 >> 12, l0 = r0 & 4095;
  int t = threadIdx.x;
  for (int i = t; i < 35*64; i += 256) {
    int lr = i >> 6, c4 = (i & 63) * 4;
    int l = l0 - 3 + lr;
    float4 v = make_float4(0.f, 0.f, 0.f, 0.f);
    if (l >= 0) {
      short4v s = *(const short4v*)((const short*)zx + ((size_t)(b<<12) + l)*NPAD + 1024 + c0 + c4);
      v = make_float4(sbf(s[0]), sbf(s[1]), sbf(s[2]), sbf(s[3]));
    }
    *(float4*)&tile[lr][c4] = v;
  }
  __syncthreads();
  int c = c0 + t;
  float w0 = cw[c*4+0], w1 = cw[c*4+1], w2 = cw[c*4+2], w3 = cw[c*4+3];
  float bias = cb[c];
  float x0 = tile[0][t], x1 = tile[1][t], x2 = tile[2][t];
  if (c0 < DIN) {
    int h = c >> 6;
    const float* dtp = dt + (size_t)r0*NH + h;
    __hip_bfloat16* xo = xtg + ((size_t)(b*DIN + c))*SEQL + l0;
    for (int lb = 0; lb < 4; lb++) {
      short8 pk;
      #pragma unroll
      for (int jj = 0; jj < 8; jj++) {
        int l = lb*8 + jj;
        float x3 = tile[l+3][t];
        float acc = bias + w0*x0 + w1*x1 + w2*x2 + w3*x3;
        float sv = acc / (1.f + __expf(-acc));
        pk[jj] = bfs(sv * dtp[(size_t)l*NH]);
        x0 = x1; x1 = x2; x2 = x3;
      }
      *(short8*)(xo + lb*8) = pk;
    }
  } else {
    int n = c - DIN;
    __hip_bfloat16* bo = (n < DSTATE) ? (btg + ((size_t)(b*DSTATE + n))*SEQL + l0) : nullptr;
    for (int lb = 0; lb < 4; lb++) {
      short8 pk;
      #pragma unroll
      for (int jj = 0; jj < 8; jj++) {
        int l = lb*8 + jj;
        float x3 = tile[l+3][t];
        float acc = bias + w0*x0 + w1*x1 + w2*x2 + w3*x3;
        float sv = acc / (1.f + __expf(-acc));
        short bv = bfs(sv);
        bcb[(size_t)(r0 + l)*256 + n] = *(__hip_bfloat16*)&bv;
        pk[jj] = bv;
        x0 = x1; x1 = x2; x2 = x3;
      }
      if (bo) *(short8*)(bo + lb*8) = pk;
    }
  }
}

// ---------------- SSD pre-scan: chunk states (step4), bf16 out, 512 thr / 8 waves ----------------
__global__ __launch_bounds__(512, 6) void ssd_states_mfma(const __hip_bfloat16* __restrict__ xtg,
                                                          const __hip_bfloat16* __restrict__ btg,
                                                          const float* __restrict__ dt,
                                                          const float* __restrict__ Alog,
                                                          __hip_bfloat16* __restrict__ stb,
                                                          float* __restrict__ acs_buf,
                                                          float* __restrict__ alast) {
  __shared__ short sBt[128][136];   // B^T [n][q] (pure copy)
  __shared__ short sXw[64][136];    // (X·w)^T [p][q]
  __shared__ float sa[128], sw[128];
  int raw = blockIdx.x;
  int bc = (raw & 7) + ((raw >> 7) << 3);
  int h = (raw >> 3) & 15;
  int b = bc >> 5, c = bc & 31;
  int sblk = bc*16 + h;
  int t = threadIdx.x;
  int w = t >> 6, lane = t & 63, quad = lane >> 4, l16 = lane & 15;
  size_t row0 = (size_t)(b*SEQL + c*CHUNKL);
  float Ah = -__expf(Alog[h]);
  if (t < 64) {
    float d0 = dt[(row0 + 2*t)*NH + h], d1 = dt[(row0 + 2*t + 1)*NH + h];
    float v0 = d0 * Ah, v1 = d1 * Ah;
    float s2 = v0 + v1;
    #pragma unroll
    for (int off = 1; off < 64; off <<= 1) {
      float tmp = __shfl_up(s2, off);
      if (t >= off) s2 += tmp;
    }
    float tot = __shfl(s2, 63);
    float pre = s2 - (v0 + v1);
    float a0 = pre + v0, a1 = pre + v0 + v1;
    sa[2*t] = a0; sa[2*t+1] = a1;
    sw[2*t] = __expf(tot - a0); sw[2*t+1] = __expf(tot - a1);
    acs_buf[(size_t)sblk*128 + 2*t]   = a0;
    acs_buf[(size_t)sblk*128 + 2*t+1] = a1;
    if (t == 63) alast[(b*NH + h)*NCHUNK + c] = tot;
  }
  __syncthreads();
  {
    const __hip_bfloat16* xb = xtg + ((size_t)(b*DIN + h*HD))*SEQL + c*CHUNKL;
    for (int i = t; i < 64*16; i += 512) {
      int p = i >> 4, q8 = (i & 15) * 8;
      short8 v = *(const short8*)(xb + (size_t)p*SEQL + q8);
      short8 o;
      #pragma unroll
      for (int j = 0; j < 8; j++) o[j] = bfs(sbf(v[j]) * sw[q8 + j]);
      *(short8*)&sXw[p][q8] = o;
    }
    const __hip_bfloat16* bb = btg + ((size_t)(b*DSTATE))*SEQL + c*CHUNKL;
    for (int i = t; i < 128*16; i += 512) {
      int n = i >> 4, q8 = (i & 15) * 8;
      *(short8*)&sBt[n][q8] = *(const short8*)(bb + (size_t)n*SEQL + q8);
    }
  }
  __syncthreads();
  int pt4 = w >> 1, nt4 = (w & 1) * 4;
  f32x4 st[4];
  #pragma unroll
  for (int j = 0; j < 4; j++) st[j] = (f32x4){0.f,0.f,0.f,0.f};
  #pragma unroll
  for (int ks = 0; ks < 128; ks += 32) {
    short8 af = *(const short8*)&sXw[pt4*16 + l16][ks + quad*8];
    #pragma unroll
    for (int j = 0; j < 4; j++) {
      short8 bfv = *(const short8*)&sBt[(nt4+j)*16 + l16][ks + quad*8];
      st[j] = __builtin_amdgcn_mfma_f32_16x16x32_bf16(af, bfv, st[j], 0, 0, 0);
    }
  }
  __hip_bfloat16* sp = stb + (size_t)sblk*(HD*DSTATE);
  #pragma unroll
  for (int j = 0; j < 4; j++) {
    int n = (nt4+j)*16 + l16;
    #pragma unroll
    for (int rg = 0; rg < 4; rg++) {
      int p = pt4*16 + quad*4 + rg;
      sp[(size_t)p*DSTATE + n] = __float2bfloat16(st[j][rg]);
    }
  }
}

// ---------------- inter-chunk scan: bf16 in-place (chunk-state -> init-state); zeroes ssq ----------------
__global__ __launch_bounds__(256) void ssd_scan2(__hip_bfloat16* __restrict__ stb, const float* __restrict__ alast,
                                                 float* __restrict__ ssq) {
  int idx = blockIdx.x*256 + threadIdx.x;     // 2*16*8192
  if (idx < ROWS) ssq[idx] = 0.f;
  int b = idx >> 17;
  int h = (idx >> 13) & 15;
  int pn = idx & 8191;
  const float* al = alast + (b*NH + h)*NCHUNK;
  float S = 0.f;
  for (int c = 0; c < NCHUNK; c++) {
    size_t base = ((size_t)((b*NCHUNK + c)*NH + h))*8192 + pn;
    float dec = __expf(al[c]);
    float tmp = __bfloat162float(stb[base]);
    stb[base] = __float2bfloat16(S);
    S = dec*S + tmp;
  }
}

// ---------------- SSD post-scan + gate, double-buffered per-head X/S staging ----------------
__global__ __launch_bounds__(1024, 4) void ssd_post_mfma(const __hip_bfloat16* __restrict__ bcb,
                                                         const __hip_bfloat16* __restrict__ xtg,
                                                         const float* __restrict__ dt,
                                                         const __hip_bfloat16* __restrict__ stb,
                                                         const float* __restrict__ acs_buf,
                                                         const float* __restrict__ Dvec,
                                                         const __hip_bfloat16* __restrict__ zx,
                                                         float* __restrict__ ssq,
                                                         __hip_bfloat16* __restrict__ Y) {
  __shared__ short sM[128][136];      // B panel during G; M_h per head after
  __shared__ short sXt[2][64][136];   // X^T (dt-scaled), double-buffered
  __shared__ short sS[2][64][136];    // scanned init-state, double-buffered
  __shared__ float sa[4][128];
  __shared__ float sdt4[4][128];
  __shared__ float ssrow[128];
  int raw = blockIdx.x;            // 0..255
  int xcd = raw & 7, slot = raw >> 3;
  int bc = xcd*8 + (slot >> 2);    // bijective: 4 blocks of one (b,c) on one XCD
  int hg = slot & 3;
  int b = bc >> 5, c = bc & 31;
  int t = threadIdx.x;
  int w = t >> 6, lane = t & 63, quad = lane >> 4, l16 = lane & 15;
  size_t row0 = (size_t)(b*SEQL + c*CHUNKL);
  const __hip_bfloat16* bcrow = bcb + row0*256;
  int mt = w >> 1, nt1 = (w & 1) * 4, pt3 = (w & 1) * 2;
  if (t < 128) ssrow[t] = 0.f;
  // hoist C fragments into registers
  short8 af[4];
  #pragma unroll
  for (int k = 0; k < 4; k++)
    af[k] = *(const short8*)(bcrow + (size_t)(mt*16 + l16)*256 + 128 + k*32 + quad*8);
  // stage B panel into sM region
  for (int i = t; i < 128*16; i += 1024) {
    int q = i >> 4, n8 = (i & 15) * 8;
    *(short8*)&sM[q][n8] = *(const short8*)(bcrow + (size_t)q*256 + n8);
  }
  // stage sa/sdt for the 4 heads
  if (t < 512) {
    int hh = t >> 7, q = t & 127;
    int h = hg*4 + hh;
    sa[hh][q]   = acs_buf[(size_t)(bc*16 + h)*128 + q];
    sdt4[hh][q] = dt[(row0 + q)*NH + h];
  }
  // stage head 0's X and S into buffer 0
  {
    int h = hg*4;
    const __hip_bfloat16* xb = xtg + ((size_t)(b*DIN + h*HD))*SEQL + c*CHUNKL;
    int p = t >> 4, q8 = (t & 15) * 8;
    *(short8*)&sXt[0][p][q8] = *(const short8*)(xb + (size_t)p*SEQL + q8);
    const __hip_bfloat16* sbase = stb + (size_t)(bc*16 + h)*(HD*DSTATE);
    *(short8*)&sS[0][p][q8] = *(const short8*)(sbase + (size_t)p*DSTATE + q8);
  }
  __syncthreads();
  // G = C·B^T once — kept live in g[4] for all 4 heads
  f32x4 g[4];
  #pragma unroll
  for (int j = 0; j < 4; j++) g[j] = (f32x4){0.f,0.f,0.f,0.f};
  #pragma unroll
  for (int ks = 0; ks < 4; ks++) {
    #pragma unroll
    for (int j = 0; j < 4; j++) {
      short8 bfv = *(const short8*)&sM[(nt1+j)*16 + l16][ks*32 + quad*8];
      g[j] = __builtin_amdgcn_mfma_f32_16x16x32_bf16(af[ks], bfv, g[j], 0, 0, 0);
    }
  }
  __syncthreads();   // B reads done; sM region free for M
  for (int hh = 0; hh < 4; hh++) {
    int h = hg*4 + hh;
    int cur = hh & 1;
    // write M_h = L_h ⊙ G into sM
    #pragma unroll
    for (int j = 0; j < 4; j++) {
      int s = (nt1+j)*16 + l16;
      #pragma unroll
      for (int rg = 0; rg < 4; rg++) {
        int q = mt*16 + quad*4 + rg;
        float m = (s <= q) ? g[j][rg] * __expf(sa[hh][q] - sa[hh][s]) : 0.f;
        sM[q][s] = bfs(m);
      }
    }
    __syncthreads();   // (A) publishes M_h + previously staged X/S[cur]
    // issue next head's X/S staging into the OTHER buffer (overlaps with MFMA below)
    if (hh < 3) {
      int h2 = h + 1;
      const __hip_bfloat16* xb = xtg + ((size_t)(b*DIN + h2*HD))*SEQL + c*CHUNKL;
      int p = t >> 4, q8 = (t & 15) * 8;
      *(short8*)&sXt[cur^1][p][q8] = *(const short8*)(xb + (size_t)p*SEQL + q8);
      const __hip_bfloat16* sbase2 = stb + (size_t)(bc*16 + h2)*(HD*DSTATE);
      *(short8*)&sS[cur^1][p][q8] = *(const short8*)(sbase2 + (size_t)p*DSTATE + q8);
    }
    // Ydiag = M_h·X_h  and  Yoff = C·S_h  (read buffer cur)
    f32x4 y4[2], yo[2];
    y4[0] = (f32x4){0.f,0.f,0.f,0.f}; y4[1] = (f32x4){0.f,0.f,0.f,0.f};
    yo[0] = (f32x4){0.f,0.f,0.f,0.f}; yo[1] = (f32x4){0.f,0.f,0.f,0.f};
    #pragma unroll
    for (int ks = 0; ks < 4; ks++) {
      short8 mf = *(const short8*)&sM[mt*16 + l16][ks*32 + quad*8];
      #pragma unroll
      for (int j = 0; j < 2; j++) {
        short8 xv = *(const short8*)&sXt[cur][(pt3+j)*16 + l16][ks*32 + quad*8];
        y4[j] = __builtin_amdgcn_mfma_f32_16x16x32_bf16(mf, xv, y4[j], 0, 0, 0);
        short8 sv = *(const short8*)&sS[cur][(pt3+j)*16 + l16][ks*32 + quad*8];
        yo[j] = __builtin_amdgcn_mfma_f32_16x16x32_bf16(af[ks], sv, yo[j], 0, 0, 0);
      }
    }
    // epilogue: v = (Yd + e^a·Yoff + D·x) * silu(z); write bf16 yz; reduce Σv² per row
    float Dh = Dvec[h];
    float part[4];
    #pragma unroll
    for (int rg = 0; rg < 4; rg++) {
      int q = mt*16 + quad*4 + rg;
      float ea = __expf(sa[hh][q]);
      float drdt = Dh / sdt4[hh][q];
      float pr = 0.f;
      #pragma unroll
      for (int j = 0; j < 2; j++) {
        int p = (pt3+j)*16 + l16;
        int ch = h*HD + p;
        float yv = y4[j][rg] + ea*yo[j][rg] + drdt*sbf(sXt[cur][p][q]);
        float z = sbf(*((const short*)zx + (row0+q)*NPAD + ch));
        float v = yv * z / (1.f + __expf(-z));
        Y[(row0 + q)*DIN + ch] = __float2bfloat16(v);
        pr += v*v;
      }
      part[rg] = pr;
    }
    #pragma unroll
    for (int rg = 0; rg < 4; rg++) {
      float pv = part[rg];
      #pragma unroll
      for (int off = 1; off < 16; off <<= 1) pv += __shfl_xor(pv, off);
      if (l16 == 0) atomicAdd(&ssrow[mt*16 + quad*4 + rg], pv);
    }
    __syncthreads();   // (B) sM reads done before next M write; staged X/S drained
  }
  if (t < 128) atomicAdd(&ssq[row0 + t], ssrow[t]);
}

extern "C" void kernel_launch(void* const* d_in, const int* in_sizes, int n_in,
                              void* d_out, int out_size, void* d_ws, size_t ws_size,
                              hipStream_t stream) {
  (void)in_sizes; (void)n_in; (void)out_size; (void)ws_size;
  const float* x    = (const float*)d_in[0];
  const float* Wi   = (const float*)d_in[1];
  const float* cw   = (const float*)d_in[2];
  const float* cb   = (const float*)d_in[3];
  const float* dtb  = (const float*)d_in[4];
  const float* Alog = (const float*)d_in[5];
  const float* Dv   = (const float*)d_in[6];
  const float* rw   = (const float*)d_in[7];
  const float* Wo   = (const float*)d_in[8];
  const float* lnw  = (const float*)d_in[9];
  const float* lnb  = (const float*)d_in[10];
  const float* flnw = (const float*)d_in[11];
  const float* flnb = (const float*)d_in[12];
  float* out = (float*)d_out;

  float* p = (float*)d_ws;
  float* buf_h   = p; p += (size_t)ROWS*DM;
  float* buf_dt  = p; p += (size_t)ROWS*NH;
  float* buf_acs = p; p += (size_t)BQ*NCHUNK*NH*CHUNKL;
  float* buf_al  = p; p += (size_t)BQ*NH*NCHUNK;
  float* buf_ssq = p; p += (size_t)ROWS;
  __hip_bfloat16* bp = (__hip_bfloat16*)p;
  __hip_bfloat16* buf_zx = bp; bp += (size_t)ROWS*NPAD;      // bf16 zx (z | xBC), stride 2304
  __hip_bfloat16* wi_b = bp; bp += (size_t)6*NPAD*DM;
  __hip_bfloat16* wo_b = bp; bp += (size_t)6*DM*DIN;
  __hip_bfloat16* hn_b = bp;                                 // shares region with yz
  __hip_bfloat16* Ybuf = bp; bp += (size_t)ROWS*DIN;
  __hip_bfloat16* bcb  = bp; bp += (size_t)ROWS*256;         // B|C natural bf16
  __hip_bfloat16* xtg  = bp; bp += (size_t)BQ*DIN*SEQL;      // X^T * dt, bf16
  __hip_bfloat16* btg  = bp; bp += (size_t)BQ*DSTATE*SEQL;   // B^T bf16
  __hip_bfloat16* stb  = bp; bp += (size_t)BQ*NCHUNK*NH*HD*DSTATE; // chunk states -> init states (in-place scan)

  cvt_wi<<<6*NPAD*DM/256, 256, 0, stream>>>(Wi, wi_b);
  cvt_wo<<<6*DM*DIN/256, 256, 0, stream>>>(Wo, rw, wo_b);

  for (int i = 0; i < 6; i++) {
    const float* hin = (i == 0) ? x : buf_h;
    ln_dt_kernel<<<ROWS, 256, 0, stream>>>(hin, lnw + i*DM, lnb + i*DM,
                                           Wi + (size_t)i*DINPROJ*DM, dtb + i*NH, hn_b, buf_dt);
    gemm_nt_obf16<<<2304, 256, 0, stream>>>(
        hn_b, wi_b + (size_t)i*NPAD*DM, buf_zx);
    conv_tiled<<<dim3(CONVDIM/256, ROWS/32), 256, 0, stream>>>(
        buf_zx, cw + (size_t)i*CONVDIM*DCONV, cb + i*CONVDIM, buf_dt,
        bcb, xtg, btg);
    ssd_states_mfma<<<BQ*NCHUNK*NH, 512, 0, stream>>>(
        xtg, btg, buf_dt, Alog + i*NH, stb, buf_acs, buf_al);
    ssd_scan2<<<BQ*NH*HD*DSTATE/256, 256, 0, stream>>>(stb, buf_al, buf_ssq);
    ssd_post_mfma<<<BQ*NCHUNK*4, 1024, 0, stream>>>(
        bcb, xtg, buf_dt, stb, buf_acs, Dv + i*NH, buf_zx, buf_ssq, Ybuf);
    gemm_nt_addf32<<<512, 256, 0, stream>>>(
        Ybuf, wo_b + (size_t)i*DM*DIN, buf_ssq, hin, buf_h);
  }
  ln_kernel<<<ROWS, 256, 0, stream>>>(buf_h, flnw, flnb, out, nullptr);
}